// Round 1
// baseline (182.522 us; speedup 1.0000x reference)
//
#include <hip/hip_runtime.h>
#include <math.h>

#define N 4096
#define D 128
#define BM 64
#define BN 64
#define JS 8
#define JCH (N / JS)       // 512 columns per block
#define PSTR 132           // padded LDS row stride (floats)
#define A_COEF 10.0f
#define B_COEF 2.0f
#define BASEV 0.5f
#define BIGV 1e30f

// ---------------- Pass 1: per-(row, j-slice) hardest-pos/neg partials ----------------
__global__ __launch_bounds__(256, 2)
void k_pass1(const float* __restrict__ x, const int* __restrict__ tgt,
             float* __restrict__ minp, float* __restrict__ maxp)
{
    __shared__ float Als[BM * PSTR];
    __shared__ float Bls[BN * PSTR];
    const int tid = threadIdx.x;
    const int tx = tid & 15, ty = tid >> 4;
    const int i0 = blockIdx.x * BM;
    const int js = blockIdx.y;

    // stage A rows (64 x 128 f32) coalesced, float4
#pragma unroll
    for (int s = 0; s < 8; ++s) {
        int idx = tid + s * 256;
        int r = idx >> 5, c4 = (idx & 31) << 2;
        *(float4*)&Als[r * PSTR + c4] = *(const float4*)&x[(i0 + r) * D + c4];
    }

    int   tgA[4];
    float mnp[4], mxn[4];
#pragma unroll
    for (int u = 0; u < 4; ++u) {
        tgA[u] = tgt[i0 + ty + 16 * u];
        mnp[u] = BIGV; mxn[u] = -BIGV;
    }

    for (int jt = 0; jt < JCH / BN; ++jt) {
        const int j0 = js * JCH + jt * BN;
        __syncthreads();
#pragma unroll
        for (int s = 0; s < 8; ++s) {
            int idx = tid + s * 256;
            int r = idx >> 5, c4 = (idx & 31) << 2;
            *(float4*)&Bls[r * PSTR + c4] = *(const float4*)&x[(j0 + r) * D + c4];
        }
        __syncthreads();

        float acc[4][4];
#pragma unroll
        for (int u = 0; u < 4; ++u)
#pragma unroll
            for (int v = 0; v < 4; ++v) acc[u][v] = 0.f;

#pragma unroll 4
        for (int k = 0; k < D; k += 4) {
            float4 a[4], b[4];
#pragma unroll
            for (int u = 0; u < 4; ++u) a[u] = *(const float4*)&Als[(ty + 16 * u) * PSTR + k];
#pragma unroll
            for (int v = 0; v < 4; ++v) b[v] = *(const float4*)&Bls[(tx + 16 * v) * PSTR + k];
#pragma unroll
            for (int u = 0; u < 4; ++u)
#pragma unroll
                for (int v = 0; v < 4; ++v)
                    acc[u][v] += a[u].x * b[v].x + a[u].y * b[v].y +
                                 a[u].z * b[v].z + a[u].w * b[v].w;
        }

#pragma unroll
        for (int v = 0; v < 4; ++v) {
            int tb = tgt[j0 + tx + 16 * v];
#pragma unroll
            for (int u = 0; u < 4; ++u) {
                float s = acc[u][v];
                if (tgA[u] == tb) { if (s < 1.0f) mnp[u] = fminf(mnp[u], s); }
                else              { mxn[u] = fmaxf(mxn[u], s); }
            }
        }
    }

    // reduce across the 16 tx lanes (consecutive lanes within a wave)
#pragma unroll
    for (int m = 1; m < 16; m <<= 1) {
#pragma unroll
        for (int u = 0; u < 4; ++u) {
            mnp[u] = fminf(mnp[u], __shfl_xor(mnp[u], m, 64));
            mxn[u] = fmaxf(mxn[u], __shfl_xor(mxn[u], m, 64));
        }
    }
    if (tx == 0) {
#pragma unroll
        for (int u = 0; u < 4; ++u) {
            minp[js * N + i0 + ty + 16 * u] = mnp[u];
            maxp[js * N + i0 + ty + 16 * u] = mxn[u];
        }
    }
}

// ---------------- Reduce partials -> min_pos / max_neg ----------------
__global__ void k_reduce(const float* __restrict__ minp, const float* __restrict__ maxp,
                         float* __restrict__ minpos, float* __restrict__ maxneg)
{
    int i = blockIdx.x * blockDim.x + threadIdx.x;
    if (i < N) {
        float mn = BIGV, mx = -BIGV;
#pragma unroll
        for (int js = 0; js < JS; ++js) {
            mn = fminf(mn, minp[js * N + i]);
            mx = fmaxf(mx, maxp[js * N + i]);
        }
        minpos[i] = mn;
        maxneg[i] = mx;
    }
}

// ---------------- Pass 2: mined exp-sums and counts ----------------
__global__ __launch_bounds__(256, 2)
void k_pass2(const float* __restrict__ x, const int* __restrict__ tgt,
             const float* __restrict__ marg, const float* __restrict__ wgt,
             const int* __restrict__ hm,
             const float* __restrict__ minpos, const float* __restrict__ maxneg,
             float* __restrict__ posp, float* __restrict__ negp,
             float* __restrict__ app,  float* __restrict__ anp)
{
    __shared__ float Als[BM * PSTR];
    __shared__ float Bls[BN * PSTR];
    const int tid = threadIdx.x;
    const int tx = tid & 15, ty = tid >> 4;
    const int i0 = blockIdx.x * BM;
    const int js = blockIdx.y;
    const int mode = hm[0];

#pragma unroll
    for (int s = 0; s < 8; ++s) {
        int idx = tid + s * 256;
        int r = idx >> 5, c4 = (idx & 31) << 2;
        *(float4*)&Als[r * PSTR + c4] = *(const float4*)&x[(i0 + r) * D + c4];
    }

    int   tgA[4];
    float mg[4], wt[4], mnp_i[4], mxn_i[4];
    float ps[4], ns[4], apc[4], anc[4];
#pragma unroll
    for (int u = 0; u < 4; ++u) {
        int row = i0 + ty + 16 * u;
        tgA[u] = tgt[row];
        mg[u] = marg[row]; wt[u] = wgt[row];
        mnp_i[u] = minpos[row]; mxn_i[u] = maxneg[row];
        ps[u] = 0.f; ns[u] = 0.f; apc[u] = 0.f; anc[u] = 0.f;
    }

    for (int jt = 0; jt < JCH / BN; ++jt) {
        const int j0 = js * JCH + jt * BN;
        __syncthreads();
#pragma unroll
        for (int s = 0; s < 8; ++s) {
            int idx = tid + s * 256;
            int r = idx >> 5, c4 = (idx & 31) << 2;
            *(float4*)&Bls[r * PSTR + c4] = *(const float4*)&x[(j0 + r) * D + c4];
        }
        __syncthreads();

        float acc[4][4];
#pragma unroll
        for (int u = 0; u < 4; ++u)
#pragma unroll
            for (int v = 0; v < 4; ++v) acc[u][v] = 0.f;

#pragma unroll 4
        for (int k = 0; k < D; k += 4) {
            float4 a[4], b[4];
#pragma unroll
            for (int u = 0; u < 4; ++u) a[u] = *(const float4*)&Als[(ty + 16 * u) * PSTR + k];
#pragma unroll
            for (int v = 0; v < 4; ++v) b[v] = *(const float4*)&Bls[(tx + 16 * v) * PSTR + k];
#pragma unroll
            for (int u = 0; u < 4; ++u)
#pragma unroll
                for (int v = 0; v < 4; ++v)
                    acc[u][v] += a[u].x * b[v].x + a[u].y * b[v].y +
                                 a[u].z * b[v].z + a[u].w * b[v].w;
        }

#pragma unroll
        for (int v = 0; v < 4; ++v) {
            int tb = tgt[j0 + tx + 16 * v];
#pragma unroll
            for (int u = 0; u < 4; ++u) {
                float s = acc[u][v];
                bool same = (tgA[u] == tb);
                if (mode == 1) {
                    float wsim = s * wt[u];
                    if (same) {
                        if (s < 1.0f && (mxn_i[u] - s + mg[u] > 0.f)) {
                            ps[u] += __expf(-B_COEF * (wsim - BASEV));
                            apc[u] += 1.f;
                        }
                    } else {
                        if (s + mg[u] - mnp_i[u] > 0.f) {
                            ns[u] += __expf(A_COEF * (wsim - BASEV));
                            anc[u] += 1.f;
                        }
                    }
                } else {
                    if (same) {
                        if (s < 1.0f) {
                            ps[u] += __expf(-B_COEF * (s - BASEV - mg[u]));
                            apc[u] += 1.f;
                        }
                    } else {
                        ns[u] += __expf(A_COEF * (s - BASEV + mg[u]));
                        anc[u] += 1.f;
                    }
                }
            }
        }
    }

#pragma unroll
    for (int m = 1; m < 16; m <<= 1) {
#pragma unroll
        for (int u = 0; u < 4; ++u) {
            ps[u]  += __shfl_xor(ps[u],  m, 64);
            ns[u]  += __shfl_xor(ns[u],  m, 64);
            apc[u] += __shfl_xor(apc[u], m, 64);
            anc[u] += __shfl_xor(anc[u], m, 64);
        }
    }
    if (tx == 0) {
#pragma unroll
        for (int u = 0; u < 4; ++u) {
            int row = i0 + ty + 16 * u;
            posp[js * N + row] = ps[u];
            negp[js * N + row] = ns[u];
            app[js * N + row]  = apc[u];
            anp[js * N + row]  = anc[u];
        }
    }
}

// ---------------- Final per-row: loss_i, validity, ap/an out ----------------
__global__ __launch_bounds__(256)
void k_final(const float* __restrict__ posp, const float* __restrict__ negp,
             const float* __restrict__ app,  const float* __restrict__ anp,
             const int* __restrict__ hm, float* __restrict__ out,
             float* __restrict__ lpart)
{
    __shared__ float red[4];
    int i = blockIdx.x * 256 + threadIdx.x;
    float ps = 0.f, ns = 0.f, ap = 0.f, an = 0.f;
#pragma unroll
    for (int js = 0; js < JS; ++js) {
        ps += posp[js * N + i];
        ns += negp[js * N + i];
        ap += app[js * N + i];
        an += anp[js * N + i];
    }
    float loss_i = (2.0f / B_COEF) * log1pf(ps) + (2.0f / A_COEF) * log1pf(ns);
    if (hm[0] == 1) {
        bool valid = (ap + an) >= 1.0f;
        if (!valid) { loss_i = 0.f; ap = 0.f; an = 0.f; }
    }
    out[1 + i]     = ap;
    out[1 + N + i] = an;

    // block-reduce loss_i
    float l = loss_i;
#pragma unroll
    for (int m = 32; m; m >>= 1) l += __shfl_down(l, m, 64);
    if ((threadIdx.x & 63) == 0) red[threadIdx.x >> 6] = l;
    __syncthreads();
    if (threadIdx.x == 0) lpart[blockIdx.x] = red[0] + red[1] + red[2] + red[3];
}

__global__ void k_loss(const float* __restrict__ lpart, float* __restrict__ out)
{
    float v = (threadIdx.x < 16) ? lpart[threadIdx.x] : 0.f;
#pragma unroll
    for (int m = 32; m; m >>= 1) v += __shfl_down(v, m, 64);
    if (threadIdx.x == 0) out[0] = v / (float)N;
}

extern "C" void kernel_launch(void* const* d_in, const int* in_sizes, int n_in,
                              void* d_out, int out_size, void* d_ws, size_t ws_size,
                              hipStream_t stream)
{
    (void)in_sizes; (void)n_in; (void)out_size; (void)ws_size;
    const float* x    = (const float*)d_in[0];
    const int*   tgt  = (const int*)d_in[1];
    const float* marg = (const float*)d_in[2];
    const float* wgt  = (const float*)d_in[3];
    const int*   hm   = (const int*)d_in[4];
    float* out = (float*)d_out;
    float* ws  = (float*)d_ws;

    float* minp   = ws;                  // JS*N
    float* maxp   = ws + JS * N;         // JS*N
    float* minpos = ws + 2 * JS * N;     // N
    float* maxneg = minpos + N;          // N
    float* posp   = maxneg + N;          // JS*N
    float* negp   = posp + JS * N;       // JS*N
    float* app    = posp + 2 * JS * N;   // JS*N
    float* anp    = posp + 3 * JS * N;   // JS*N
    float* lpart  = posp + 4 * JS * N;   // 16

    dim3 g1(N / BM, JS);
    k_pass1<<<g1, 256, 0, stream>>>(x, tgt, minp, maxp);
    k_reduce<<<N / 256, 256, 0, stream>>>(minp, maxp, minpos, maxneg);
    k_pass2<<<g1, 256, 0, stream>>>(x, tgt, marg, wgt, hm, minpos, maxneg,
                                    posp, negp, app, anp);
    k_final<<<N / 256, 256, 0, stream>>>(posp, negp, app, anp, hm, out, lpart);
    k_loss<<<1, 64, 0, stream>>>(lpart, out);
}

// Round 2
// 85.984 us; speedup vs baseline: 2.1227x; 2.1227x over previous
//
#include <hip/hip_runtime.h>
#include <math.h>

#define N 4096
#define D 128
#define NT 32                 // 4096/128 tiles per dim
#define NBLK (NT*(NT+1)/2)    // 528 upper-triangular tiles
#define LSTR 40               // LDS row stride (32 + 8 pad), keeps 16B alignment
#define BIGV 1e30f

typedef __bf16 bf16x8 __attribute__((ext_vector_type(8)));
typedef float  f32x4  __attribute__((ext_vector_type(4)));

__device__ inline ushort bf16_rne(float f) {
  unsigned u = __float_as_uint(f);
  unsigned r = u + 0x7FFFu + ((u >> 16) & 1u);
  return (ushort)(r >> 16);
}

// ---------------- split x (f32) -> hi/lo bf16 ----------------
__global__ __launch_bounds__(256)
void k_convert(const float* __restrict__ x, ushort* __restrict__ xh, ushort* __restrict__ xl)
{
  int i = (blockIdx.x * 256 + threadIdx.x) * 4;
  float4 v = *(const float4*)&x[i];
  ushort4 h, l;
  float hv;
  h.x = bf16_rne(v.x); hv = __uint_as_float((unsigned)h.x << 16); l.x = bf16_rne(v.x - hv);
  h.y = bf16_rne(v.y); hv = __uint_as_float((unsigned)h.y << 16); l.y = bf16_rne(v.y - hv);
  h.z = bf16_rne(v.z); hv = __uint_as_float((unsigned)h.z << 16); l.z = bf16_rne(v.z - hv);
  h.w = bf16_rne(v.w); hv = __uint_as_float((unsigned)h.w << 16); l.w = bf16_rne(v.w - hv);
  *(ushort4*)&xh[i] = h;
  *(ushort4*)&xl[i] = l;
}

// ---------------- Pass 1: hardest-pos/neg partials (triangular MFMA) ----------------
__global__ __launch_bounds__(256, 2)
void k_pass1(const ushort* __restrict__ xh, const ushort* __restrict__ xl,
             const int* __restrict__ tgt,
             float* __restrict__ minp, float* __restrict__ maxp)
{
  __shared__ __bf16 Ah[128*LSTR], Al[128*LSTR], Bh[128*LSTR], Bl[128*LSTR];
  __shared__ int tgI[128], tgJ[128];
  __shared__ float redmn[256], redmx[256];

  int bid = blockIdx.x;
  int I = 0, rem = bid;
  while (rem >= NT - I) { rem -= NT - I; ++I; }
  int J = I + rem;
  const int i0 = I * 128, j0 = J * 128;
  const bool diag = (I == J);

  const int tid = threadIdx.x;
  const int l = tid & 63, wid = tid >> 6;
  const int wr = wid >> 1, wc = wid & 1;
  const int g = l >> 4, c = l & 15;

  if (tid < 128) { tgI[tid] = tgt[i0 + tid]; tgJ[tid] = tgt[j0 + tid]; }

  f32x4 acc[4][4];
#pragma unroll
  for (int m = 0; m < 4; ++m)
#pragma unroll
    for (int n = 0; n < 4; ++n) acc[m][n] = f32x4{0.f, 0.f, 0.f, 0.f};

  const __bf16* BhP = diag ? Ah : Bh;
  const __bf16* BlP = diag ? Al : Bl;

  for (int kt = 0; kt < 4; ++kt) {
    __syncthreads();
    {
      int r = tid >> 2, q = tid & 3;
#pragma unroll
      for (int h = 0; h < 2; ++h) {
        int row = r + h * 64;
        int go = (i0 + row) * D + kt * 32 + q * 8;
        *(int4*)&Ah[row * LSTR + q * 8] = *(const int4*)&xh[go];
        *(int4*)&Al[row * LSTR + q * 8] = *(const int4*)&xl[go];
        if (!diag) {
          int gob = (j0 + row) * D + kt * 32 + q * 8;
          *(int4*)&Bh[row * LSTR + q * 8] = *(const int4*)&xh[gob];
          *(int4*)&Bl[row * LSTR + q * 8] = *(const int4*)&xl[gob];
        }
      }
    }
    __syncthreads();

    bf16x8 fah[4], fal[4];
#pragma unroll
    for (int m = 0; m < 4; ++m) {
      int row = wr * 64 + m * 16 + c;
      fah[m] = *(const bf16x8*)&Ah[row * LSTR + g * 8];
      fal[m] = *(const bf16x8*)&Al[row * LSTR + g * 8];
    }
#pragma unroll
    for (int n = 0; n < 4; ++n) {
      int col = wc * 64 + n * 16 + c;
      bf16x8 fbh = *(const bf16x8*)&BhP[col * LSTR + g * 8];
      bf16x8 fbl = *(const bf16x8*)&BlP[col * LSTR + g * 8];
#pragma unroll
      for (int m = 0; m < 4; ++m) {
        acc[m][n] = __builtin_amdgcn_mfma_f32_16x16x32_bf16(fah[m], fbh, acc[m][n], 0, 0, 0);
        acc[m][n] = __builtin_amdgcn_mfma_f32_16x16x32_bf16(fah[m], fbl, acc[m][n], 0, 0, 0);
        acc[m][n] = __builtin_amdgcn_mfma_f32_16x16x32_bf16(fal[m], fbh, acc[m][n], 0, 0, 0);
      }
    }
  }

  // ----- I-side epilogue: per-row min-pos / max-neg over this tile's cols -----
  int tgc[4];
#pragma unroll
  for (int n = 0; n < 4; ++n) tgc[n] = tgJ[wc * 64 + n * 16 + c];

#pragma unroll
  for (int m = 0; m < 4; ++m)
#pragma unroll
    for (int jj = 0; jj < 4; ++jj) {
      int row_loc = wr * 64 + m * 16 + g * 4 + jj;
      int trow = tgI[row_loc];
      float mn = BIGV, mx = -BIGV;
#pragma unroll
      for (int n = 0; n < 4; ++n) {
        float s = acc[m][n][jj];
        if (trow == tgc[n]) { if (s < 1.0f) mn = fminf(mn, s); }
        else                  mx = fmaxf(mx, s);
      }
#pragma unroll
      for (int msk = 1; msk < 16; msk <<= 1) {
        mn = fminf(mn, __shfl_xor(mn, msk, 64));
        mx = fmaxf(mx, __shfl_xor(mx, msk, 64));
      }
      if (c == 0) { redmn[wc * 128 + row_loc] = mn; redmx[wc * 128 + row_loc] = mx; }
    }
  __syncthreads();
  if (tid < 128) {
    minp[J * N + i0 + tid] = fminf(redmn[tid], redmn[128 + tid]);
    maxp[J * N + i0 + tid] = fmaxf(redmx[tid], redmx[128 + tid]);
  }

  // ----- J-side epilogue (transposed attribution) -----
  if (!diag) {
    __syncthreads();
    float mnn[4], mxx[4];
#pragma unroll
    for (int n = 0; n < 4; ++n) { mnn[n] = BIGV; mxx[n] = -BIGV; }
#pragma unroll
    for (int m = 0; m < 4; ++m)
#pragma unroll
      for (int jj = 0; jj < 4; ++jj) {
        int row_loc = wr * 64 + m * 16 + g * 4 + jj;
        int tcol = tgI[row_loc];
#pragma unroll
        for (int n = 0; n < 4; ++n) {
          float s = acc[m][n][jj];
          if (tgc[n] == tcol) { if (s < 1.0f) mnn[n] = fminf(mnn[n], s); }
          else                  mxx[n] = fmaxf(mxx[n], s);
        }
      }
#pragma unroll
    for (int n = 0; n < 4; ++n) {
#pragma unroll
      for (int msk = 16; msk < 64; msk <<= 1) {
        mnn[n] = fminf(mnn[n], __shfl_xor(mnn[n], msk, 64));
        mxx[n] = fmaxf(mxx[n], __shfl_xor(mxx[n], msk, 64));
      }
    }
    if (g == 0) {
#pragma unroll
      for (int n = 0; n < 4; ++n) {
        redmn[wr * 128 + wc * 64 + n * 16 + c] = mnn[n];
        redmx[wr * 128 + wc * 64 + n * 16 + c] = mxx[n];
      }
    }
    __syncthreads();
    if (tid < 128) {
      minp[I * N + j0 + tid] = fminf(redmn[tid], redmn[128 + tid]);
      maxp[I * N + j0 + tid] = fmaxf(redmx[tid], redmx[128 + tid]);
    }
  }
}

// ---------------- combine partials ----------------
__global__ __launch_bounds__(256)
void k_reduce(const float* __restrict__ minp, const float* __restrict__ maxp,
              float* __restrict__ minpos, float* __restrict__ maxneg)
{
  int i = blockIdx.x * 256 + threadIdx.x;
  float mn = BIGV, mx = -BIGV;
#pragma unroll
  for (int p = 0; p < NT; ++p) {
    mn = fminf(mn, minp[p * N + i]);
    mx = fmaxf(mx, maxp[p * N + i]);
  }
  minpos[i] = mn;
  maxneg[i] = mx;
}

// ---------------- Pass 2: mined exp-sums + counts (triangular MFMA) ----------------
__global__ __launch_bounds__(256, 2)
void k_pass2(const ushort* __restrict__ xh, const ushort* __restrict__ xl,
             const int* __restrict__ tgt,
             const float* __restrict__ marg, const float* __restrict__ wgt,
             const int* __restrict__ hm,
             const float* __restrict__ minpos, const float* __restrict__ maxneg,
             float* __restrict__ posp, float* __restrict__ negp,
             float* __restrict__ app,  float* __restrict__ anp)
{
  __shared__ __bf16 Ah[128*LSTR], Al[128*LSTR], Bh[128*LSTR], Bl[128*LSTR];
  __shared__ int tgI[128], tgJ[128];
  __shared__ float rdI0[128], rdI1[128], rdI2[128], rdI3[128];
  __shared__ float rdJ0[128], rdJ1[128], rdJ2[128], rdJ3[128];
  __shared__ float redps[256], redns[256], redap[256], redan[256];

  int bid = blockIdx.x;
  int I = 0, rem = bid;
  while (rem >= NT - I) { rem -= NT - I; ++I; }
  int J = I + rem;
  const int i0 = I * 128, j0 = J * 128;
  const bool diag = (I == J);

  const int tid = threadIdx.x;
  const int l = tid & 63, wid = tid >> 6;
  const int wr = wid >> 1, wc = wid & 1;
  const int g = l >> 4, c = l & 15;
  const int mode = hm[0];

  if (tid < 128) {
    tgI[tid] = tgt[i0 + tid]; tgJ[tid] = tgt[j0 + tid];
    rdI0[tid] = minpos[i0 + tid]; rdI1[tid] = maxneg[i0 + tid];
    rdI2[tid] = marg[i0 + tid];   rdI3[tid] = wgt[i0 + tid];
    rdJ0[tid] = minpos[j0 + tid]; rdJ1[tid] = maxneg[j0 + tid];
    rdJ2[tid] = marg[j0 + tid];   rdJ3[tid] = wgt[j0 + tid];
  }

  f32x4 acc[4][4];
#pragma unroll
  for (int m = 0; m < 4; ++m)
#pragma unroll
    for (int n = 0; n < 4; ++n) acc[m][n] = f32x4{0.f, 0.f, 0.f, 0.f};

  const __bf16* BhP = diag ? Ah : Bh;
  const __bf16* BlP = diag ? Al : Bl;

  for (int kt = 0; kt < 4; ++kt) {
    __syncthreads();
    {
      int r = tid >> 2, q = tid & 3;
#pragma unroll
      for (int h = 0; h < 2; ++h) {
        int row = r + h * 64;
        int go = (i0 + row) * D + kt * 32 + q * 8;
        *(int4*)&Ah[row * LSTR + q * 8] = *(const int4*)&xh[go];
        *(int4*)&Al[row * LSTR + q * 8] = *(const int4*)&xl[go];
        if (!diag) {
          int gob = (j0 + row) * D + kt * 32 + q * 8;
          *(int4*)&Bh[row * LSTR + q * 8] = *(const int4*)&xh[gob];
          *(int4*)&Bl[row * LSTR + q * 8] = *(const int4*)&xl[gob];
        }
      }
    }
    __syncthreads();

    bf16x8 fah[4], fal[4];
#pragma unroll
    for (int m = 0; m < 4; ++m) {
      int row = wr * 64 + m * 16 + c;
      fah[m] = *(const bf16x8*)&Ah[row * LSTR + g * 8];
      fal[m] = *(const bf16x8*)&Al[row * LSTR + g * 8];
    }
#pragma unroll
    for (int n = 0; n < 4; ++n) {
      int col = wc * 64 + n * 16 + c;
      bf16x8 fbh = *(const bf16x8*)&BhP[col * LSTR + g * 8];
      bf16x8 fbl = *(const bf16x8*)&BlP[col * LSTR + g * 8];
#pragma unroll
      for (int m = 0; m < 4; ++m) {
        acc[m][n] = __builtin_amdgcn_mfma_f32_16x16x32_bf16(fah[m], fbh, acc[m][n], 0, 0, 0);
        acc[m][n] = __builtin_amdgcn_mfma_f32_16x16x32_bf16(fah[m], fbl, acc[m][n], 0, 0, 0);
        acc[m][n] = __builtin_amdgcn_mfma_f32_16x16x32_bf16(fal[m], fbh, acc[m][n], 0, 0, 0);
      }
    }
  }

  // ----- I-side epilogue -----
  int tgc[4];
#pragma unroll
  for (int n = 0; n < 4; ++n) tgc[n] = tgJ[wc * 64 + n * 16 + c];

#pragma unroll
  for (int m = 0; m < 4; ++m)
#pragma unroll
    for (int jj = 0; jj < 4; ++jj) {
      int row_loc = wr * 64 + m * 16 + g * 4 + jj;
      int trow = tgI[row_loc];
      float mnp = rdI0[row_loc], mxn = rdI1[row_loc];
      float mg  = rdI2[row_loc], wt  = rdI3[row_loc];
      float ps = 0.f, ns = 0.f, apv = 0.f, anv = 0.f;
#pragma unroll
      for (int n = 0; n < 4; ++n) {
        float s = acc[m][n][jj];
        bool same = (trow == tgc[n]);
        if (mode == 1) {
          float wsim = s * wt;
          if (same) {
            if (s < 1.0f && (mxn - s + mg > 0.f)) { ps += __expf(-2.f * (wsim - 0.5f)); apv += 1.f; }
          } else {
            if (s + mg - mnp > 0.f) { ns += __expf(10.f * (wsim - 0.5f)); anv += 1.f; }
          }
        } else {
          if (same) {
            if (s < 1.0f) { ps += __expf(-2.f * (s - 0.5f - mg)); apv += 1.f; }
          } else {
            ns += __expf(10.f * (s - 0.5f + mg)); anv += 1.f;
          }
        }
      }
#pragma unroll
      for (int msk = 1; msk < 16; msk <<= 1) {
        ps  += __shfl_xor(ps,  msk, 64);
        ns  += __shfl_xor(ns,  msk, 64);
        apv += __shfl_xor(apv, msk, 64);
        anv += __shfl_xor(anv, msk, 64);
      }
      if (c == 0) {
        redps[wc * 128 + row_loc] = ps;  redns[wc * 128 + row_loc] = ns;
        redap[wc * 128 + row_loc] = apv; redan[wc * 128 + row_loc] = anv;
      }
    }
  __syncthreads();
  if (tid < 128) {
    posp[J * N + i0 + tid] = redps[tid] + redps[128 + tid];
    negp[J * N + i0 + tid] = redns[tid] + redns[128 + tid];
    app [J * N + i0 + tid] = redap[tid] + redap[128 + tid];
    anp [J * N + i0 + tid] = redan[tid] + redan[128 + tid];
  }

  // ----- J-side epilogue (transposed attribution) -----
  if (!diag) {
    __syncthreads();
    float mnpJ[4], mxnJ[4], mgJ[4], wtJ[4];
#pragma unroll
    for (int n = 0; n < 4; ++n) {
      int jr = wc * 64 + n * 16 + c;
      mnpJ[n] = rdJ0[jr]; mxnJ[n] = rdJ1[jr]; mgJ[n] = rdJ2[jr]; wtJ[n] = rdJ3[jr];
    }
    float psn[4], nsn[4], apn[4], ann[4];
#pragma unroll
    for (int n = 0; n < 4; ++n) { psn[n] = 0.f; nsn[n] = 0.f; apn[n] = 0.f; ann[n] = 0.f; }
#pragma unroll
    for (int m = 0; m < 4; ++m)
#pragma unroll
      for (int jj = 0; jj < 4; ++jj) {
        int row_loc = wr * 64 + m * 16 + g * 4 + jj;
        int tcol = tgI[row_loc];
#pragma unroll
        for (int n = 0; n < 4; ++n) {
          float s = acc[m][n][jj];
          bool same = (tgc[n] == tcol);
          if (mode == 1) {
            float wsim = s * wtJ[n];
            if (same) {
              if (s < 1.0f && (mxnJ[n] - s + mgJ[n] > 0.f)) { psn[n] += __expf(-2.f * (wsim - 0.5f)); apn[n] += 1.f; }
            } else {
              if (s + mgJ[n] - mnpJ[n] > 0.f) { nsn[n] += __expf(10.f * (wsim - 0.5f)); ann[n] += 1.f; }
            }
          } else {
            if (same) {
              if (s < 1.0f) { psn[n] += __expf(-2.f * (s - 0.5f - mgJ[n])); apn[n] += 1.f; }
            } else {
              nsn[n] += __expf(10.f * (s - 0.5f + mgJ[n])); ann[n] += 1.f;
            }
          }
        }
      }
#pragma unroll
    for (int n = 0; n < 4; ++n) {
#pragma unroll
      for (int msk = 16; msk < 64; msk <<= 1) {
        psn[n] += __shfl_xor(psn[n], msk, 64);
        nsn[n] += __shfl_xor(nsn[n], msk, 64);
        apn[n] += __shfl_xor(apn[n], msk, 64);
        ann[n] += __shfl_xor(ann[n], msk, 64);
      }
    }
    if (g == 0) {
#pragma unroll
      for (int n = 0; n < 4; ++n) {
        int col_loc = wc * 64 + n * 16 + c;
        redps[wr * 128 + col_loc] = psn[n]; redns[wr * 128 + col_loc] = nsn[n];
        redap[wr * 128 + col_loc] = apn[n]; redan[wr * 128 + col_loc] = ann[n];
      }
    }
    __syncthreads();
    if (tid < 128) {
      posp[I * N + j0 + tid] = redps[tid] + redps[128 + tid];
      negp[I * N + j0 + tid] = redns[tid] + redns[128 + tid];
      app [I * N + j0 + tid] = redap[tid] + redap[128 + tid];
      anp [I * N + j0 + tid] = redan[tid] + redan[128 + tid];
    }
  }
}

// ---------------- final per-row ----------------
__global__ __launch_bounds__(256)
void k_final(const float* __restrict__ posp, const float* __restrict__ negp,
             const float* __restrict__ app,  const float* __restrict__ anp,
             const int* __restrict__ hm, float* __restrict__ out,
             float* __restrict__ lpart)
{
  __shared__ float red[4];
  int i = blockIdx.x * 256 + threadIdx.x;
  float ps = 0.f, ns = 0.f, ap = 0.f, an = 0.f;
#pragma unroll
  for (int p = 0; p < NT; ++p) {
    ps += posp[p * N + i]; ns += negp[p * N + i];
    ap += app[p * N + i];  an += anp[p * N + i];
  }
  float loss_i = 1.0f * log1pf(ps) + 0.2f * log1pf(ns);
  if (hm[0] == 1 && (ap + an) < 1.0f) { loss_i = 0.f; ap = 0.f; an = 0.f; }
  out[1 + i]     = ap;
  out[1 + N + i] = an;

  float v = loss_i;
#pragma unroll
  for (int msk = 32; msk; msk >>= 1) v += __shfl_down(v, msk, 64);
  if ((threadIdx.x & 63) == 0) red[threadIdx.x >> 6] = v;
  __syncthreads();
  if (threadIdx.x == 0) lpart[blockIdx.x] = red[0] + red[1] + red[2] + red[3];
}

__global__ void k_loss(const float* __restrict__ lpart, float* __restrict__ out)
{
  float v = (threadIdx.x < 16) ? lpart[threadIdx.x] : 0.f;
#pragma unroll
  for (int msk = 32; msk; msk >>= 1) v += __shfl_down(v, msk, 64);
  if (threadIdx.x == 0) out[0] = v / (float)N;
}

extern "C" void kernel_launch(void* const* d_in, const int* in_sizes, int n_in,
                              void* d_out, int out_size, void* d_ws, size_t ws_size,
                              hipStream_t stream)
{
  (void)in_sizes; (void)n_in; (void)out_size; (void)ws_size;
  const float* x    = (const float*)d_in[0];
  const int*   tgt  = (const int*)d_in[1];
  const float* marg = (const float*)d_in[2];
  const float* wgt  = (const float*)d_in[3];
  const int*   hm   = (const int*)d_in[4];
  float* out = (float*)d_out;

  char* base = (char*)d_ws;
  ushort* xh   = (ushort*)base;                        // 1 MB
  ushort* xl   = (ushort*)(base + (1 << 20));          // 1 MB
  float* minp   = (float*)(base + (2 << 20));          // 32*N f32 = 512 KB
  float* maxp   = minp + NT * N;
  float* minpos = maxp + NT * N;                       // 16 KB
  float* maxneg = minpos + N;
  float* posp   = maxneg + N;                          // 4 x 512 KB
  float* negp   = posp + NT * N;
  float* app    = negp + NT * N;
  float* anp    = app  + NT * N;
  float* lpart  = anp  + NT * N;                       // 64 B

  k_convert<<<(N * D) / (256 * 4), 256, 0, stream>>>(x, xh, xl);
  k_pass1<<<NBLK, 256, 0, stream>>>(xh, xl, tgt, minp, maxp);
  k_reduce<<<N / 256, 256, 0, stream>>>(minp, maxp, minpos, maxneg);
  k_pass2<<<NBLK, 256, 0, stream>>>(xh, xl, tgt, marg, wgt, hm, minpos, maxneg,
                                    posp, negp, app, anp);
  k_final<<<N / 256, 256, 0, stream>>>(posp, negp, app, anp, hm, out, lpart);
  k_loss<<<1, 64, 0, stream>>>(lpart, out);
}